// Round 3
// baseline (150.440 us; speedup 1.0000x reference)
//
#include <hip/hip_runtime.h>

#define RES 0.1f

constexpr int B_ = 512;
constexpr int N_ = 8192;        // points per batch
constexpr int H_ = 200;
constexpr int W_ = 200;
constexpr int MAP = H_ * W_;    // 40000 floats = 160,000 B LDS (gfx950 has 163,840)
constexpr long long TOTAL = (long long)B_ * N_;   // 4,194,304

constexpr int TPB = 1024;       // 16 waves
constexpr int PPT = 8;          // points per thread (8192/1024)
constexpr int V4  = PPT / 2;    // float4 loads per thread (2 points each)

__global__ __launch_bounds__(TPB) void collision_lds(
    const float* __restrict__ opState,
    const float* __restrict__ envs,
    float* __restrict__ partial)
{
    __shared__ float smap[MAP];          // 160,000 B
    const int b   = blockIdx.x;          // one batch per block
    const int tid = threadIdx.x;

    // ---- 1. issue ALL point loads first (registers, no LDS dependency) ----
    // layout (N,2): one float4 = two consecutive points. 16 B/lane coalesced.
    const float4* pts4 = (const float4*)((const float2*)opState + (long long)b * N_);
    float4 p[V4];
    #pragma unroll
    for (int k = 0; k < V4; ++k)
        p[k] = pts4[tid + k * TPB];      // covers 4096 float4 = 8192 points

    // ---- 2. stage map: coalesced float4 (10000 vec4 over 1024 threads) ----
    {
        const float4* m4 = (const float4*)(envs + (long long)b * MAP);
        float4* s4 = (float4*)smap;
        #pragma unroll
        for (int j = 0; j < 10; ++j) {
            int idx = tid + j * TPB;
            if (idx < MAP / 4) s4[idx] = m4[idx];
        }
    }
    __syncthreads();

    // ---- 3. compute from registers + LDS ----
    float acc = 0.0f;
    #pragma unroll
    for (int k = 0; k < V4; ++k) {
        #pragma unroll
        for (int h = 0; h < 2; ++h) {
            const float qx = h ? p[k].z : p[k].x;
            const float qy = h ? p[k].w : p[k].y;

            bool out_range = (qx < -9.9f) | (qx > 9.9f) |
                             (qy < -9.9f) | (qy > 9.9f);

            float px = fminf(fmaxf(qx, -9.9f), 9.9f);
            float py = fminf(fmaxf(qy, -9.9f), 9.9f);

            float pmx = px - 0.5f * RES;
            float pmy = py - 0.5f * RES;

            int ix = (int)floorf((pmx + 10.0f) * 10.0f);
            int iy = (int)floorf((pmy + 10.0f) * 10.0f);

            float ipx = ((float)ix + 0.5f) * RES - 10.0f;
            float ipy = ((float)iy + 0.5f) * RES - 10.0f;

            float dx = (px - ipx) * 10.0f;
            float dy = (py - ipy) * 10.0f;

            int base = ix * W_ + iy;
            float v00 = smap[base];
            float v01 = smap[base + 1];
            float v10 = smap[base + W_];
            float v11 = smap[base + W_ + 1];

            float vx0 = (1.0f - dx) * v00 + dx * v10;
            float vx1 = (1.0f - dx) * v01 + dx * v11;
            float v   = (1.0f - dy) * vx0 + dy * vx1;

            float dists = out_range ? -1.0f : v;
            float viod  = 10.0f * (0.3f - dists);
            float r     = viod > 0.0f ? viod : 0.0f;
            acc += r * r;
        }
    }

    // ---- 4. block reduction: wave64 shuffle, then cross-wave via LDS ----
    #pragma unroll
    for (int off = 32; off > 0; off >>= 1)
        acc += __shfl_down(acc, off, 64);

    __shared__ float sacc[TPB / 64];     // 16 waves
    const int lane = tid & 63;
    const int wid  = tid >> 6;
    if (lane == 0) sacc[wid] = acc;
    __syncthreads();

    if (tid == 0) {
        float s = 0.0f;
        #pragma unroll
        for (int w = 0; w < TPB / 64; ++w) s += sacc[w];
        partial[b] = s;
    }
}

__global__ __launch_bounds__(512) void collision_final(
    const float* __restrict__ partial,
    float* __restrict__ out)
{
    float acc = partial[threadIdx.x];    // exactly 512 partials

    #pragma unroll
    for (int off = 32; off > 0; off >>= 1)
        acc += __shfl_down(acc, off, 64);

    __shared__ float sacc[8];
    const int lane = threadIdx.x & 63;
    const int wid  = threadIdx.x >> 6;
    if (lane == 0) sacc[wid] = acc;
    __syncthreads();

    if (threadIdx.x == 0) {
        float s = 0.0f;
        #pragma unroll
        for (int w = 0; w < 8; ++w) s += sacc[w];
        out[0] = s / (float)TOTAL;
    }
}

extern "C" void kernel_launch(void* const* d_in, const int* in_sizes, int n_in,
                              void* d_out, int out_size, void* d_ws, size_t ws_size,
                              hipStream_t stream) {
    const float* opState = (const float*)d_in[0];   // (512, 8192, 2) f32
    const float* envs    = (const float*)d_in[1];   // (512, 1, 200, 200) f32
    float* out     = (float*)d_out;                 // scalar f32
    float* partial = (float*)d_ws;                  // 512 floats of scratch

    collision_lds<<<B_, TPB, 0, stream>>>(opState, envs, partial);
    collision_final<<<1, 512, 0, stream>>>(partial, out);
}

// Round 4
// 149.602 us; speedup vs baseline: 1.0056x; 1.0056x over previous
//
#include <hip/hip_runtime.h>
#include <hip/hip_bf16.h>

#define RES 0.1f

constexpr int B_ = 512;
constexpr int N_ = 8192;        // points per batch
constexpr int H_ = 200;
constexpr int W_ = 200;
constexpr int MAP = H_ * W_;    // 40000 elems; bf16 -> 80,000 B LDS (2 blocks/CU)
constexpr long long TOTAL = (long long)B_ * N_;   // 4,194,304

constexpr int TPB = 1024;       // 16 waves; 2 blocks/CU = 32 waves/CU (max)
constexpr int PPT = 8;          // points per thread
constexpr int V4  = PPT / 2;    // float4 loads (2 points each)

__global__ __launch_bounds__(TPB) void collision_lds(
    const float* __restrict__ opState,
    const float* __restrict__ envs,
    float* __restrict__ partial)
{
    __shared__ __hip_bfloat16 smap[MAP];   // 80,000 B — two blocks fit per CU
    const int b   = blockIdx.x;            // one batch per block
    const int tid = threadIdx.x;

    // ---- 1. issue point loads first (registers; overlaps staging) ----
    const float4* pts4 = (const float4*)((const float2*)opState + (long long)b * N_);
    float4 p[V4];
    #pragma unroll
    for (int k = 0; k < V4; ++k)
        p[k] = pts4[tid + k * TPB];

    // ---- 2. stage map: coalesced float4 read -> bf16x4 LDS write ----
    {
        const float4* m4 = (const float4*)(envs + (long long)b * MAP);
        ushort4* s4 = (ushort4*)smap;
        #pragma unroll
        for (int j = 0; j < 10; ++j) {
            int idx = tid + j * TPB;
            if (idx < MAP / 4) {
                float4 m = m4[idx];
                __hip_bfloat16 h0 = __float2bfloat16(m.x);
                __hip_bfloat16 h1 = __float2bfloat16(m.y);
                __hip_bfloat16 h2 = __float2bfloat16(m.z);
                __hip_bfloat16 h3 = __float2bfloat16(m.w);
                ushort4 u;
                u.x = *(const unsigned short*)&h0;
                u.y = *(const unsigned short*)&h1;
                u.z = *(const unsigned short*)&h2;
                u.w = *(const unsigned short*)&h3;
                s4[idx] = u;
            }
        }
    }
    __syncthreads();

    // ---- 3. compute from registers + LDS ----
    float acc = 0.0f;
    #pragma unroll
    for (int k = 0; k < V4; ++k) {
        #pragma unroll
        for (int h = 0; h < 2; ++h) {
            const float qx = h ? p[k].z : p[k].x;
            const float qy = h ? p[k].w : p[k].y;

            bool out_range = (qx < -9.9f) | (qx > 9.9f) |
                             (qy < -9.9f) | (qy > 9.9f);

            float px = fminf(fmaxf(qx, -9.9f), 9.9f);
            float py = fminf(fmaxf(qy, -9.9f), 9.9f);

            float pmx = px - 0.5f * RES;
            float pmy = py - 0.5f * RES;

            int ix = (int)floorf((pmx + 10.0f) * 10.0f);
            int iy = (int)floorf((pmy + 10.0f) * 10.0f);

            float ipx = ((float)ix + 0.5f) * RES - 10.0f;
            float ipy = ((float)iy + 0.5f) * RES - 10.0f;

            float dx = (px - ipx) * 10.0f;
            float dy = (py - ipy) * 10.0f;

            int base = ix * W_ + iy;
            float v00 = __bfloat162float(smap[base]);
            float v01 = __bfloat162float(smap[base + 1]);
            float v10 = __bfloat162float(smap[base + W_]);
            float v11 = __bfloat162float(smap[base + W_ + 1]);

            float vx0 = (1.0f - dx) * v00 + dx * v10;
            float vx1 = (1.0f - dx) * v01 + dx * v11;
            float v   = (1.0f - dy) * vx0 + dy * vx1;

            float dists = out_range ? -1.0f : v;
            float viod  = 10.0f * (0.3f - dists);
            float r     = viod > 0.0f ? viod : 0.0f;
            acc += r * r;
        }
    }

    // ---- 4. block reduction: wave64 shuffle, then cross-wave via LDS ----
    #pragma unroll
    for (int off = 32; off > 0; off >>= 1)
        acc += __shfl_down(acc, off, 64);

    __shared__ float sacc[TPB / 64];     // 16 waves
    const int lane = tid & 63;
    const int wid  = tid >> 6;
    if (lane == 0) sacc[wid] = acc;
    __syncthreads();

    if (tid == 0) {
        float s = 0.0f;
        #pragma unroll
        for (int w = 0; w < TPB / 64; ++w) s += sacc[w];
        partial[b] = s;
    }
}

__global__ __launch_bounds__(512) void collision_final(
    const float* __restrict__ partial,
    float* __restrict__ out)
{
    float acc = partial[threadIdx.x];    // exactly 512 partials

    #pragma unroll
    for (int off = 32; off > 0; off >>= 1)
        acc += __shfl_down(acc, off, 64);

    __shared__ float sacc[8];
    const int lane = threadIdx.x & 63;
    const int wid  = threadIdx.x >> 6;
    if (lane == 0) sacc[wid] = acc;
    __syncthreads();

    if (threadIdx.x == 0) {
        float s = 0.0f;
        #pragma unroll
        for (int w = 0; w < 8; ++w) s += sacc[w];
        out[0] = s / (float)TOTAL;
    }
}

extern "C" void kernel_launch(void* const* d_in, const int* in_sizes, int n_in,
                              void* d_out, int out_size, void* d_ws, size_t ws_size,
                              hipStream_t stream) {
    const float* opState = (const float*)d_in[0];   // (512, 8192, 2) f32
    const float* envs    = (const float*)d_in[1];   // (512, 1, 200, 200) f32
    float* out     = (float*)d_out;                 // scalar f32
    float* partial = (float*)d_ws;                  // 512 floats of scratch

    collision_lds<<<B_, TPB, 0, stream>>>(opState, envs, partial);
    collision_final<<<1, 512, 0, stream>>>(partial, out);
}

// Round 5
// 146.829 us; speedup vs baseline: 1.0246x; 1.0189x over previous
//
#include <hip/hip_runtime.h>
#include <hip/hip_bf16.h>

#define RES 0.1f

constexpr int B_ = 512;
constexpr int N_ = 8192;        // points per batch
constexpr int H_ = 200;
constexpr int W_ = 200;
constexpr int MAP = H_ * W_;    // 40000 bf16 elems = 80,000 B (+pad)
constexpr long long TOTAL = (long long)B_ * N_;   // 4,194,304

constexpr int TPB = 1024;       // 16 waves; 2 blocks/CU = 32 waves/CU
constexpr int PPT = 8;          // points per thread
constexpr int V4  = PPT / 2;    // float4 point loads (2 points each)
constexpr int BATCH = 4;        // points gathered together (ILP window)

__global__ __launch_bounds__(TPB, 8) void collision_lds(
    const float* __restrict__ opState,
    const float* __restrict__ envs,
    float* __restrict__ partial)
{
    // +4 pad: unconditional read of word jrow+1 can touch 1 word past map end
    __shared__ __hip_bfloat16 smap[MAP + 4];
    const int b   = blockIdx.x;            // one batch per block
    const int tid = threadIdx.x;

    // ---- 1. issue point loads first (registers; overlaps staging) ----
    const float4* pts4 = (const float4*)((const float2*)opState + (long long)b * N_);
    float4 p[V4];
    #pragma unroll
    for (int k = 0; k < V4; ++k)
        p[k] = pts4[tid + k * TPB];

    // ---- 2. stage map: coalesced float4 read -> bf16x4 LDS write ----
    {
        const float4* m4 = (const float4*)(envs + (long long)b * MAP);
        ushort4* s4 = (ushort4*)smap;
        #pragma unroll
        for (int j = 0; j < 10; ++j) {
            int idx = tid + j * TPB;
            if (idx < MAP / 4) {
                float4 m = m4[idx];
                __hip_bfloat16 h0 = __float2bfloat16(m.x);
                __hip_bfloat16 h1 = __float2bfloat16(m.y);
                __hip_bfloat16 h2 = __float2bfloat16(m.z);
                __hip_bfloat16 h3 = __float2bfloat16(m.w);
                ushort4 u;
                u.x = *(const unsigned short*)&h0;
                u.y = *(const unsigned short*)&h1;
                u.z = *(const unsigned short*)&h2;
                u.w = *(const unsigned short*)&h3;
                s4[idx] = u;
            }
        }
    }
    __syncthreads();

    // ---- 3. compute: 2 batches of 4 points, batched addr -> batched LDS ----
    const unsigned int* smapw = (const unsigned int*)smap;
    float acc = 0.0f;

    #pragma unroll
    for (int bat = 0; bat < PPT / BATCH; ++bat) {
        int   jr0[BATCH];      // word index, row ix
        int   jr1[BATCH];      // word index, row ix+1
        int   sel[BATCH];      // iy parity
        float dxA[BATCH], dyA[BATCH];
        bool  orA[BATCH];

        #pragma unroll
        for (int t = 0; t < BATCH; ++t) {
            const int pt = bat * BATCH + t;           // 0..7
            const float4 pv = p[pt >> 1];
            const float qx = (pt & 1) ? pv.z : pv.x;
            const float qy = (pt & 1) ? pv.w : pv.y;

            orA[t] = (qx < -9.9f) | (qx > 9.9f) | (qy < -9.9f) | (qy > 9.9f);

            float px = fminf(fmaxf(qx, -9.9f), 9.9f);
            float py = fminf(fmaxf(qy, -9.9f), 9.9f);

            float pmx = px - 0.5f * RES;
            float pmy = py - 0.5f * RES;

            int ix = (int)floorf((pmx + 10.0f) * 10.0f);
            int iy = (int)floorf((pmy + 10.0f) * 10.0f);

            float ipx = ((float)ix + 0.5f) * RES - 10.0f;
            float ipy = ((float)iy + 0.5f) * RES - 10.0f;

            dxA[t] = (px - ipx) * 10.0f;
            dyA[t] = (py - ipy) * 10.0f;

            const int base = ix * W_ + iy;
            jr0[t] = base >> 1;
            jr1[t] = (base + W_) >> 1;
            sel[t] = base & 1;
        }

        // issue all 16 word reads back-to-back (merge to ds_read2_b32)
        unsigned int w00[BATCH], w01[BATCH], w10[BATCH], w11[BATCH];
        #pragma unroll
        for (int t = 0; t < BATCH; ++t) {
            w00[t] = smapw[jr0[t]];
            w01[t] = smapw[jr0[t] + 1];
            w10[t] = smapw[jr1[t]];
            w11[t] = smapw[jr1[t] + 1];
        }

        #pragma unroll
        for (int t = 0; t < BATCH; ++t) {
            // extract (col iy, col iy+1) bf16 from the two dwords of each row
            unsigned int c00 = sel[t] ? (w00[t] >> 16)      : (w00[t] & 0xffffu);
            unsigned int c01 = sel[t] ? (w01[t] & 0xffffu)  : (w00[t] >> 16);
            unsigned int c10 = sel[t] ? (w10[t] >> 16)      : (w10[t] & 0xffffu);
            unsigned int c11 = sel[t] ? (w11[t] & 0xffffu)  : (w10[t] >> 16);

            c00 <<= 16; c01 <<= 16; c10 <<= 16; c11 <<= 16;
            float v00 = __uint_as_float(c00);
            float v01 = __uint_as_float(c01);
            float v10 = __uint_as_float(c10);
            float v11 = __uint_as_float(c11);

            float dx = dxA[t], dy = dyA[t];
            float vx0 = (1.0f - dx) * v00 + dx * v10;
            float vx1 = (1.0f - dx) * v01 + dx * v11;
            float v   = (1.0f - dy) * vx0 + dy * vx1;

            float dists = orA[t] ? -1.0f : v;
            float viod  = 10.0f * (0.3f - dists);
            float r     = viod > 0.0f ? viod : 0.0f;
            acc += r * r;
        }
    }

    // ---- 4. block reduction ----
    #pragma unroll
    for (int off = 32; off > 0; off >>= 1)
        acc += __shfl_down(acc, off, 64);

    __shared__ float sacc[TPB / 64];     // 16 waves
    const int lane = tid & 63;
    const int wid  = tid >> 6;
    if (lane == 0) sacc[wid] = acc;
    __syncthreads();

    if (tid == 0) {
        float s = 0.0f;
        #pragma unroll
        for (int w = 0; w < TPB / 64; ++w) s += sacc[w];
        partial[b] = s;
    }
}

__global__ __launch_bounds__(512) void collision_final(
    const float* __restrict__ partial,
    float* __restrict__ out)
{
    float acc = partial[threadIdx.x];    // exactly 512 partials

    #pragma unroll
    for (int off = 32; off > 0; off >>= 1)
        acc += __shfl_down(acc, off, 64);

    __shared__ float sacc[8];
    const int lane = threadIdx.x & 63;
    const int wid  = threadIdx.x >> 6;
    if (lane == 0) sacc[wid] = acc;
    __syncthreads();

    if (threadIdx.x == 0) {
        float s = 0.0f;
        #pragma unroll
        for (int w = 0; w < 8; ++w) s += sacc[w];
        out[0] = s / (float)TOTAL;
    }
}

extern "C" void kernel_launch(void* const* d_in, const int* in_sizes, int n_in,
                              void* d_out, int out_size, void* d_ws, size_t ws_size,
                              hipStream_t stream) {
    const float* opState = (const float*)d_in[0];   // (512, 8192, 2) f32
    const float* envs    = (const float*)d_in[1];   // (512, 1, 200, 200) f32
    float* out     = (float*)d_out;                 // scalar f32
    float* partial = (float*)d_ws;                  // 512 floats of scratch

    collision_lds<<<B_, TPB, 0, stream>>>(opState, envs, partial);
    collision_final<<<1, 512, 0, stream>>>(partial, out);
}